// Round 2
// baseline (11939.377 us; speedup 1.0000x reference)
//
#include <hip/hip_runtime.h>
#include <hip/hip_bf16.h>

#define NN 15135
#define BS 8
#define FIN 64
#define HD 128
#define EE 242160
#define HFC 512
#define NCLS 10

#define M_ROWS (BS * NN)          // 121080
#define HBUF   (M_ROWS * HD)      // 15498240 floats per h buffer

// ---------------- init: zero deg, g = bfc ----------------
__global__ void k_init(float* __restrict__ deg, float* __restrict__ g,
                       const float* __restrict__ bfc) {
    int i = blockIdx.x * 256 + threadIdx.x;
    if (i < NN) deg[i] = 0.f;
    if (i < M_ROWS) g[i] = bfc[0];
}

// ---------------- degree histogram ----------------
__global__ void k_deg(const int* __restrict__ dst, float* __restrict__ deg) {
    int e = blockIdx.x * 256 + threadIdx.x;
    if (e < EE) unsafeAtomicAdd(&deg[dst[e]], 1.0f);
}

__global__ void k_dinv(float* __restrict__ deg) {
    int i = blockIdx.x * 256 + threadIdx.x;
    if (i < NN) deg[i] = rsqrtf(deg[i] + 1.0f);   // +1 self loop
}

// ---------------- fp32 GEMM: Y[M,128] = X[M,K] @ W[K,128] ----------------
// 64 rows x 128 cols per block, K staged in chunks of 32.
__global__ __launch_bounds__(256) void k_gemm(const float* __restrict__ X,
                                              const float* __restrict__ W,
                                              float* __restrict__ Y,
                                              int M, int K) {
    __shared__ float xs[64][33];    // +1 pad -> max 2-way bank conflict (free)
    __shared__ float ws[32][128];
    const int tid = threadIdx.x;
    const int tc = tid & 31;        // col4 group: cols 4*tc..4*tc+3
    const int tr = tid >> 5;        // 0..7 -> rows tr*8..tr*8+7
    const int row0 = blockIdx.x * 64;

    float4 acc[8];
#pragma unroll
    for (int i = 0; i < 8; i++) acc[i] = make_float4(0.f, 0.f, 0.f, 0.f);

    for (int k0 = 0; k0 < K; k0 += 32) {
        // X tile: 64 rows x 32 cols = 512 float4 loads, 2 per thread
#pragma unroll
        for (int i = 0; i < 2; i++) {
            int f4 = tid + i * 256;
            int r2 = f4 >> 3, c4 = f4 & 7;
            int grow = row0 + r2;
            float4 v = make_float4(0.f, 0.f, 0.f, 0.f);
            if (grow < M) v = *(const float4*)&X[(size_t)grow * K + k0 + c4 * 4];
            xs[r2][c4 * 4 + 0] = v.x;
            xs[r2][c4 * 4 + 1] = v.y;
            xs[r2][c4 * 4 + 2] = v.z;
            xs[r2][c4 * 4 + 3] = v.w;
        }
        // W tile: 32 rows x 128 cols = 1024 float4, 4 per thread
#pragma unroll
        for (int i = 0; i < 4; i++) {
            int f4 = tid + i * 256;
            int r2 = f4 >> 5, c4 = f4 & 31;
            *(float4*)&ws[r2][c4 * 4] = *(const float4*)&W[(size_t)(r2 + k0) * HD + c4 * 4];
        }
        __syncthreads();
#pragma unroll
        for (int kk = 0; kk < 32; ++kk) {
            float4 w = *(float4*)&ws[kk][tc * 4];
#pragma unroll
            for (int r = 0; r < 8; r++) {
                float a = xs[tr * 8 + r][kk];
                acc[r].x += a * w.x; acc[r].y += a * w.y;
                acc[r].z += a * w.z; acc[r].w += a * w.w;
            }
        }
        __syncthreads();
    }
#pragma unroll
    for (int r = 0; r < 8; r++) {
        int grow = row0 + tr * 8 + r;
        if (grow < M) *(float4*)&Y[(size_t)grow * HD + tc * 4] = acc[r];
    }
}

// ---------------- self-loop init: out = xl * dinv[n]^2 ----------------
__global__ void k_selfloop(const float* __restrict__ xl, const float* __restrict__ dinv,
                           float* __restrict__ outb) {
    unsigned i4 = blockIdx.x * 256 + threadIdx.x;     // float4 index
    if (i4 >= (unsigned)(HBUF / 4)) return;
    unsigned i = i4 * 4;
    unsigned row = i >> 7;            // b*NN + n
    unsigned n = row % NN;
    float dv = dinv[n];
    float w = dv * dv;
    float4 v = *(const float4*)&xl[i];
    v.x *= w; v.y *= w; v.z *= w; v.w *= w;
    *(float4*)&outb[i] = v;
}

// ---------------- edge scatter: out[:,d,:] += xl[:,s,:] * dinv[s]*dinv[d] ----------------
__global__ __launch_bounds__(256) void k_scatter(const float* __restrict__ xl,
                                                 const int* __restrict__ src,
                                                 const int* __restrict__ dst,
                                                 const float* __restrict__ dinv,
                                                 float* __restrict__ outb) {
    const int e = blockIdx.x;
    const int s = src[e], d = dst[e];
    const float w = dinv[s] * dinv[d];
    const int t = threadIdx.x;
    const int b = t >> 5;
    const int c = (t & 31) << 2;
    const float4 v = *(const float4*)&xl[((size_t)b * NN + s) * HD + c];
    float* o = &outb[((size_t)b * NN + d) * HD + c];
    unsafeAtomicAdd(&o[0], v.x * w);
    unsafeAtomicAdd(&o[1], v.y * w);
    unsafeAtomicAdd(&o[2], v.z * w);
    unsafeAtomicAdd(&o[3], v.w * w);
}

// ---------------- finalize: h = relu(buf + bias) in-place; g += h . Wfc[:,l] ----------------
__global__ __launch_bounds__(256) void k_finalize(float* __restrict__ hbuf,
                                                  const float* __restrict__ bias,
                                                  const float* __restrict__ Wfc, int lidx,
                                                  float* __restrict__ g) {
    const int t = threadIdx.x;
    const int h = t & 127;
    const int rp = t >> 7;                       // 0 or 1
    const size_t row = (size_t)blockIdx.x * 2 + rp;
    float v = hbuf[row * HD + h] + bias[h];
    v = fmaxf(v, 0.f);
    hbuf[row * HD + h] = v;
    float p = v * Wfc[h * 3 + lidx];
#pragma unroll
    for (int off = 32; off > 0; off >>= 1) p += __shfl_down(p, off);
    __shared__ float red[4];
    if ((t & 63) == 0) red[t >> 6] = p;
    __syncthreads();
    if (t == 0)   g[row] += red[0] + red[1];
    if (t == 128) g[row] += red[2] + red[3];
}

// ---------------- z[8,512] = relu(g[8,N] @ Wl1[N,512] + bl1) ----------------
__global__ __launch_bounds__(256) void k_fc1(const float* __restrict__ g,
                                             const float* __restrict__ Wl1,
                                             const float* __restrict__ bl1,
                                             float* __restrict__ z) {
    const int c0 = blockIdx.x * 64;
    const int cl = threadIdx.x & 63;
    const int nq = threadIdx.x >> 6;     // 0..3
    const int c = c0 + cl;
    float acc[BS];
#pragma unroll
    for (int b = 0; b < BS; b++) acc[b] = 0.f;
    for (int n = nq; n < NN; n += 4) {
        float w = Wl1[(size_t)n * HFC + c];
#pragma unroll
        for (int b = 0; b < BS; b++) acc[b] += g[b * NN + n] * w;
    }
    __shared__ float red[4][64][BS];     // 8 KB
#pragma unroll
    for (int b = 0; b < BS; b++) red[nq][cl][b] = acc[b];
    __syncthreads();
    if (nq == 0) {
        float bb = bl1[c];
#pragma unroll
        for (int b = 0; b < BS; b++) {
            float s = red[0][cl][b] + red[1][cl][b] + red[2][cl][b] + red[3][cl][b] + bb;
            z[b * HFC + c] = fmaxf(s, 0.f);
        }
    }
}

// ---------------- logits + log_softmax ----------------
__global__ void k_head(const float* __restrict__ z, const float* __restrict__ Wl2,
                       const float* __restrict__ bl2, float* __restrict__ out) {
    __shared__ float lg[BS][NCLS];
    const int t = threadIdx.x;
    if (t < BS * NCLS) {
        int b = t / NCLS, c = t % NCLS;
        float a = bl2[c];
        for (int k = 0; k < HFC; k++) a += z[b * HFC + k] * Wl2[k * NCLS + c];
        lg[b][c] = a;
    }
    __syncthreads();
    if (t < BS * NCLS) {
        int b = t / NCLS, c = t % NCLS;
        float m = -1e30f;
#pragma unroll
        for (int j = 0; j < NCLS; j++) m = fmaxf(m, lg[b][j]);
        float s = 0.f;
#pragma unroll
        for (int j = 0; j < NCLS; j++) s += expf(lg[b][j] - m);
        out[b * NCLS + c] = lg[b][c] - m - logf(s);
    }
}

extern "C" void kernel_launch(void* const* d_in, const int* in_sizes, int n_in,
                              void* d_out, int out_size, void* d_ws, size_t ws_size,
                              hipStream_t stream) {
    const float* x   = (const float*)d_in[0];
    const int*   ei  = (const int*)d_in[1];
    const float* W1  = (const float*)d_in[2];
    const float* b1  = (const float*)d_in[3];
    const float* W2  = (const float*)d_in[4];
    const float* b2  = (const float*)d_in[5];
    const float* W3  = (const float*)d_in[6];
    const float* b3  = (const float*)d_in[7];
    const float* Wfc = (const float*)d_in[8];
    const float* bfc = (const float*)d_in[9];
    const float* Wl1 = (const float*)d_in[10];
    const float* bl1 = (const float*)d_in[11];
    const float* Wl2 = (const float*)d_in[12];
    const float* bl2 = (const float*)d_in[13];
    float* out = (float*)d_out;

    const int* srcp = ei;
    const int* dstp = ei + EE;

    float* ws  = (float*)d_ws;
    float* dinv = ws;                    // 15135 (padded 15360)
    float* g    = ws + 15360;            // 121080
    float* z    = ws + 136448;           // 4096
    float* tmp  = ws + 140544;           // HBUF
    float* sA   = tmp + HBUF;
    float* sB   = sA + HBUF;

    const int gemm_grid = (M_ROWS + 63) / 64;
    const int sl_grid   = HBUF / 4 / 256;           // exact: 15135
    const int fin_grid  = M_ROWS / 2;               // 60540

    k_init<<<(M_ROWS + 255) / 256, 256, 0, stream>>>(dinv, g, bfc);
    k_deg<<<(EE + 255) / 256, 256, 0, stream>>>(dstp, dinv);
    k_dinv<<<(NN + 255) / 256, 256, 0, stream>>>(dinv);

    // conv1: x[.,64] -> sA = h1
    k_gemm<<<gemm_grid, 256, 0, stream>>>(x, W1, tmp, M_ROWS, FIN);
    k_selfloop<<<sl_grid, 256, 0, stream>>>(tmp, dinv, sA);
    k_scatter<<<EE, 256, 0, stream>>>(tmp, srcp, dstp, dinv, sA);
    k_finalize<<<fin_grid, 256, 0, stream>>>(sA, b1, Wfc, 0, g);

    // conv2: sA -> sB = h2
    k_gemm<<<gemm_grid, 256, 0, stream>>>(sA, W2, tmp, M_ROWS, HD);
    k_selfloop<<<sl_grid, 256, 0, stream>>>(tmp, dinv, sB);
    k_scatter<<<EE, 256, 0, stream>>>(tmp, srcp, dstp, dinv, sB);
    k_finalize<<<fin_grid, 256, 0, stream>>>(sB, b2, Wfc, 1, g);

    // conv3: sB -> sA = h3 (h1 dead)
    k_gemm<<<gemm_grid, 256, 0, stream>>>(sB, W3, tmp, M_ROWS, HD);
    k_selfloop<<<sl_grid, 256, 0, stream>>>(tmp, dinv, sA);
    k_scatter<<<EE, 256, 0, stream>>>(tmp, srcp, dstp, dinv, sA);
    k_finalize<<<fin_grid, 256, 0, stream>>>(sA, b3, Wfc, 2, g);

    k_fc1<<<8, 256, 0, stream>>>(g, Wl1, bl1, z);
    k_head<<<1, 128, 0, stream>>>(z, Wl2, bl2, out);
}

// Round 3
// 840.610 us; speedup vs baseline: 14.2032x; 14.2032x over previous
//
#include <hip/hip_runtime.h>
#include <hip/hip_bf16.h>

#define NN 15135
#define BS 8
#define FIN 64
#define HD 128
#define EE 242160
#define HFC 512
#define NCLS 10

#define M_ROWS (BS * NN)          // 121080
#define HBUF   (M_ROWS * HD)      // 15498240 floats per h buffer

// ---------------- init: zero int degree + cursor, g = bfc ----------------
__global__ void k_init(int* __restrict__ degi, int* __restrict__ cursor,
                       float* __restrict__ g, const float* __restrict__ bfc) {
    int i = blockIdx.x * 256 + threadIdx.x;
    if (i < NN) { degi[i] = 0; cursor[i] = 0; }
    if (i < M_ROWS) g[i] = bfc[0];
}

// ---------------- degree histogram (int) ----------------
__global__ void k_deg(const int* __restrict__ dst, int* __restrict__ degi) {
    int e = blockIdx.x * 256 + threadIdx.x;
    if (e < EE) atomicAdd(&degi[dst[e]], 1);
}

__global__ void k_dinv(const int* __restrict__ degi, float* __restrict__ dinv) {
    int i = blockIdx.x * 256 + threadIdx.x;
    if (i < NN) dinv[i] = rsqrtf((float)degi[i] + 1.0f);   // +1 self loop
}

// ---------------- exclusive prefix scan of degi -> row_ptr (1 block) ----------------
#define SCAN_T 1024
#define SCAN_PER 15          // 1024*15 = 15360 >= NN
__global__ __launch_bounds__(SCAN_T) void k_scan(const int* __restrict__ degi,
                                                 int* __restrict__ row_ptr) {
    __shared__ int part[SCAN_T];
    const int t = threadIdx.x;
    const int base = t * SCAN_PER;
    int loc[SCAN_PER];
    int s = 0;
#pragma unroll
    for (int i = 0; i < SCAN_PER; i++) {
        int v = (base + i < NN) ? degi[base + i] : 0;
        loc[i] = s; s += v;
    }
    part[t] = s;
    __syncthreads();
    for (int off = 1; off < SCAN_T; off <<= 1) {
        int v = (t >= off) ? part[t - off] : 0;
        __syncthreads();
        part[t] += v;
        __syncthreads();
    }
    int before = (t == 0) ? 0 : part[t - 1];
#pragma unroll
    for (int i = 0; i < SCAN_PER; i++)
        if (base + i < NN) row_ptr[base + i] = before + loc[i];
    if (t == SCAN_T - 1) row_ptr[NN] = part[SCAN_T - 1];
}

// ---------------- bucket fill: CSR by dst ----------------
__global__ void k_bucket(const int* __restrict__ src, const int* __restrict__ dst,
                         const int* __restrict__ row_ptr, int* __restrict__ cursor,
                         const float* __restrict__ dinv,
                         int* __restrict__ s_idx, float* __restrict__ wts) {
    int e = blockIdx.x * 256 + threadIdx.x;
    if (e >= EE) return;
    int s = src[e], d = dst[e];
    int pos = atomicAdd(&cursor[d], 1);
    int idx = row_ptr[d] + pos;
    s_idx[idx] = s;
    wts[idx] = dinv[s] * dinv[d];
}

// ---------------- fp32 GEMM: Y[M,128] = X[M,K] @ W[K,128] ----------------
__global__ __launch_bounds__(256) void k_gemm(const float* __restrict__ X,
                                              const float* __restrict__ W,
                                              float* __restrict__ Y,
                                              int M, int K) {
    __shared__ float xs[64][33];
    __shared__ float ws[32][128];
    const int tid = threadIdx.x;
    const int tc = tid & 31;
    const int tr = tid >> 5;
    const int row0 = blockIdx.x * 64;

    float4 acc[8];
#pragma unroll
    for (int i = 0; i < 8; i++) acc[i] = make_float4(0.f, 0.f, 0.f, 0.f);

    for (int k0 = 0; k0 < K; k0 += 32) {
#pragma unroll
        for (int i = 0; i < 2; i++) {
            int f4 = tid + i * 256;
            int r2 = f4 >> 3, c4 = f4 & 7;
            int grow = row0 + r2;
            float4 v = make_float4(0.f, 0.f, 0.f, 0.f);
            if (grow < M) v = *(const float4*)&X[(size_t)grow * K + k0 + c4 * 4];
            xs[r2][c4 * 4 + 0] = v.x;
            xs[r2][c4 * 4 + 1] = v.y;
            xs[r2][c4 * 4 + 2] = v.z;
            xs[r2][c4 * 4 + 3] = v.w;
        }
#pragma unroll
        for (int i = 0; i < 4; i++) {
            int f4 = tid + i * 256;
            int r2 = f4 >> 5, c4 = f4 & 31;
            *(float4*)&ws[r2][c4 * 4] = *(const float4*)&W[(size_t)(r2 + k0) * HD + c4 * 4];
        }
        __syncthreads();
#pragma unroll
        for (int kk = 0; kk < 32; ++kk) {
            float4 w = *(float4*)&ws[kk][tc * 4];
#pragma unroll
            for (int r = 0; r < 8; r++) {
                float a = xs[tr * 8 + r][kk];
                acc[r].x += a * w.x; acc[r].y += a * w.y;
                acc[r].z += a * w.z; acc[r].w += a * w.w;
            }
        }
        __syncthreads();
    }
#pragma unroll
    for (int r = 0; r < 8; r++) {
        int grow = row0 + tr * 8 + r;
        if (grow < M) *(float4*)&Y[(size_t)grow * HD + tc * 4] = acc[r];
    }
}

// ---------------- fused aggregate: h = relu(norm-agg(xl) + bias); g += h . Wfc[:,l]
// block per dst node n; 256 threads = 8 batches x 32 lanes (float4 each)
#define ECHUNK 64
__global__ __launch_bounds__(256) void k_agg(const float* __restrict__ xl,
                                             const int* __restrict__ row_ptr,
                                             const int* __restrict__ s_idx,
                                             const float* __restrict__ wts,
                                             const float* __restrict__ dinv,
                                             const float* __restrict__ bias,
                                             const float* __restrict__ Wfc, int lidx,
                                             float* __restrict__ h, float* __restrict__ g) {
    const int n = blockIdx.x;
    const int t = threadIdx.x;
    const int b = t >> 5;
    const int l = t & 31;
    __shared__ int   ss[ECHUNK];
    __shared__ float sw[ECHUNK];

    const int e0 = row_ptr[n], e1 = row_ptr[n + 1];
    const float dv = dinv[n];
    const float w0 = dv * dv;

    const size_t selfoff = ((size_t)b * NN + n) * HD + l * 4;
    float4 v = *(const float4*)&xl[selfoff];
    float4 acc = make_float4(w0 * v.x, w0 * v.y, w0 * v.z, w0 * v.w);

    for (int c0 = e0; c0 < e1; c0 += ECHUNK) {
        int cnt = min(ECHUNK, e1 - c0);
        if (t < cnt) { ss[t] = s_idx[c0 + t]; sw[t] = wts[c0 + t]; }
        __syncthreads();
        for (int j = 0; j < cnt; j++) {
            float w = sw[j];
            int s = ss[j];
            float4 u = *(const float4*)&xl[((size_t)b * NN + s) * HD + l * 4];
            acc.x += w * u.x; acc.y += w * u.y;
            acc.z += w * u.z; acc.w += w * u.w;
        }
        __syncthreads();
    }

    float4 bb = ((const float4*)bias)[l];
    acc.x = fmaxf(acc.x + bb.x, 0.f);
    acc.y = fmaxf(acc.y + bb.y, 0.f);
    acc.z = fmaxf(acc.z + bb.z, 0.f);
    acc.w = fmaxf(acc.w + bb.w, 0.f);
    *(float4*)&h[selfoff] = acc;

    // partial g: dot with interleaved Wfc column (feat k = f*3 + lidx)
    float p = acc.x * Wfc[(l * 4 + 0) * 3 + lidx]
            + acc.y * Wfc[(l * 4 + 1) * 3 + lidx]
            + acc.z * Wfc[(l * 4 + 2) * 3 + lidx]
            + acc.w * Wfc[(l * 4 + 3) * 3 + lidx];
#pragma unroll
    for (int off = 16; off > 0; off >>= 1) p += __shfl_down(p, off, 32);
    if (l == 0) g[b * NN + n] += p;
}

// ---------------- fc1 partials: grid (8 col-blocks, 32 n-chunks) ----------------
#define FC1_CH 473            // 473*32 = 15136 >= NN
__global__ __launch_bounds__(256) void k_fc1part(const float* __restrict__ g,
                                                 const float* __restrict__ Wl1,
                                                 float* __restrict__ part) {
    const int c = blockIdx.x * 64 + (threadIdx.x & 63);
    const int nq = threadIdx.x >> 6;       // 0..3
    const int n0 = blockIdx.y * FC1_CH;
    const int n1 = min(n0 + FC1_CH, NN);
    float acc[BS];
#pragma unroll
    for (int b = 0; b < BS; b++) acc[b] = 0.f;
    for (int n = n0 + nq; n < n1; n += 4) {
        float w = Wl1[(size_t)n * HFC + c];
#pragma unroll
        for (int b = 0; b < BS; b++) acc[b] += g[b * NN + n] * w;
    }
    __shared__ float red[4][64][BS];
    const int cl = threadIdx.x & 63;
#pragma unroll
    for (int b = 0; b < BS; b++) red[nq][cl][b] = acc[b];
    __syncthreads();
    if (nq == 0) {
#pragma unroll
        for (int b = 0; b < BS; b++) {
            float s = red[0][cl][b] + red[1][cl][b] + red[2][cl][b] + red[3][cl][b];
            part[((size_t)blockIdx.y * HFC + c) * BS + b] = s;
        }
    }
}

__global__ __launch_bounds__(512) void k_fc1red(const float* __restrict__ part,
                                                const float* __restrict__ bl1,
                                                float* __restrict__ z) {
    const int c = threadIdx.x;            // 0..511
    float acc[BS];
#pragma unroll
    for (int b = 0; b < BS; b++) acc[b] = 0.f;
    for (int y = 0; y < 32; y++) {
#pragma unroll
        for (int b = 0; b < BS; b++) acc[b] += part[((size_t)y * HFC + c) * BS + b];
    }
    float bb = bl1[c];
#pragma unroll
    for (int b = 0; b < BS; b++) z[b * HFC + c] = fmaxf(acc[b] + bb, 0.f);
}

// ---------------- logits + log_softmax ----------------
__global__ void k_head(const float* __restrict__ z, const float* __restrict__ Wl2,
                       const float* __restrict__ bl2, float* __restrict__ out) {
    __shared__ float lg[BS][NCLS];
    const int t = threadIdx.x;
    if (t < BS * NCLS) {
        int b = t / NCLS, c = t % NCLS;
        float a = bl2[c];
        for (int k = 0; k < HFC; k++) a += z[b * HFC + k] * Wl2[k * NCLS + c];
        lg[b][c] = a;
    }
    __syncthreads();
    if (t < BS * NCLS) {
        int b = t / NCLS, c = t % NCLS;
        float m = -1e30f;
#pragma unroll
        for (int j = 0; j < NCLS; j++) m = fmaxf(m, lg[b][j]);
        float s = 0.f;
#pragma unroll
        for (int j = 0; j < NCLS; j++) s += expf(lg[b][j] - m);
        out[b * NCLS + c] = lg[b][c] - m - logf(s);
    }
}

extern "C" void kernel_launch(void* const* d_in, const int* in_sizes, int n_in,
                              void* d_out, int out_size, void* d_ws, size_t ws_size,
                              hipStream_t stream) {
    const float* x   = (const float*)d_in[0];
    const int*   ei  = (const int*)d_in[1];
    const float* W1  = (const float*)d_in[2];
    const float* b1  = (const float*)d_in[3];
    const float* W2  = (const float*)d_in[4];
    const float* b2  = (const float*)d_in[5];
    const float* W3  = (const float*)d_in[6];
    const float* b3  = (const float*)d_in[7];
    const float* Wfc = (const float*)d_in[8];
    const float* bfc = (const float*)d_in[9];
    const float* Wl1 = (const float*)d_in[10];
    const float* bl1 = (const float*)d_in[11];
    const float* Wl2 = (const float*)d_in[12];
    const float* bl2 = (const float*)d_in[13];
    float* out = (float*)d_out;

    const int* srcp = ei;
    const int* dstp = ei + EE;

    float* ws = (float*)d_ws;
    // layout (float units)
    float* dinv    = ws;                        // 15360
    int*   row_ptr = (int*)(ws + 15360);        // 15488
    int*   cursor  = (int*)(ws + 30848);        // 15360
    int*   degi    = (int*)(ws + 46208);        // 15360
    int*   s_idx   = (int*)(ws + 61568);        // 242176
    float* wts     = ws + 303744;               // 242176
    float* g       = ws + 545920;               // 121088
    float* z       = ws + 667008;               // 4096
    float* part    = ws + 671104;               // 131072
    float* tmp     = ws + 802176;               // HBUF
    float* hA      = tmp + HBUF;
    float* hB      = hA + HBUF;

    const int gemm_grid = (M_ROWS + 63) / 64;

    k_init<<<(M_ROWS + 255) / 256, 256, 0, stream>>>(degi, cursor, g, bfc);
    k_deg<<<(EE + 255) / 256, 256, 0, stream>>>(dstp, degi);
    k_dinv<<<(NN + 255) / 256, 256, 0, stream>>>(degi, dinv);
    k_scan<<<1, SCAN_T, 0, stream>>>(degi, row_ptr);
    k_bucket<<<(EE + 255) / 256, 256, 0, stream>>>(srcp, dstp, row_ptr, cursor, dinv, s_idx, wts);

    // conv1
    k_gemm<<<gemm_grid, 256, 0, stream>>>(x, W1, tmp, M_ROWS, FIN);
    k_agg<<<NN, 256, 0, stream>>>(tmp, row_ptr, s_idx, wts, dinv, b1, Wfc, 0, hA, g);
    // conv2
    k_gemm<<<gemm_grid, 256, 0, stream>>>(hA, W2, tmp, M_ROWS, HD);
    k_agg<<<NN, 256, 0, stream>>>(tmp, row_ptr, s_idx, wts, dinv, b2, Wfc, 1, hB, g);
    // conv3
    k_gemm<<<gemm_grid, 256, 0, stream>>>(hB, W3, tmp, M_ROWS, HD);
    k_agg<<<NN, 256, 0, stream>>>(tmp, row_ptr, s_idx, wts, dinv, b3, Wfc, 2, hA, g);

    k_fc1part<<<dim3(8, 32), 256, 0, stream>>>(g, Wl1, part);
    k_fc1red<<<1, 512, 0, stream>>>(part, bl1, z);
    k_head<<<1, 128, 0, stream>>>(z, Wl2, bl2, out);
}

// Round 4
// 626.777 us; speedup vs baseline: 19.0488x; 1.3412x over previous
//
#include <hip/hip_runtime.h>
#include <hip/hip_bf16.h>

#define NN 15135
#define BS 8
#define FIN 64
#define HD 128
#define EE 242160
#define HFC 512
#define NCLS 10

#define M_ROWS (BS * NN)          // 121080
#define M_PAD  121088             // 64 * 1892

typedef __attribute__((ext_vector_type(8))) short bf16x8;
typedef __attribute__((ext_vector_type(4))) float f32x4;

__device__ __forceinline__ unsigned short to_bf16(float f) {
    unsigned u = __float_as_uint(f);
    u = (u + 0x7fffu + ((u >> 16) & 1u)) >> 16;       // RNE
    return (unsigned short)u;
}
__device__ __forceinline__ unsigned pack2_bf16(float lo, float hi) {
    unsigned a = __float_as_uint(lo);
    unsigned b = __float_as_uint(hi);
    a = (a + 0x7fffu + ((a >> 16) & 1u)) >> 16;
    b = (b + 0x7fffu + ((b >> 16) & 1u)) & 0xffff0000u;
    return (a & 0xffffu) | b;
}

// ---------------- init ----------------
__global__ void k_init(int* __restrict__ degi, int* __restrict__ cursor) {
    int i = blockIdx.x * 256 + threadIdx.x;
    if (i < NN) { degi[i] = 0; cursor[i] = 0; }
}

__global__ void k_deg(const int* __restrict__ dst, int* __restrict__ degi) {
    int e = blockIdx.x * 256 + threadIdx.x;
    if (e < EE) atomicAdd(&degi[dst[e]], 1);
}

__global__ void k_dinv(const int* __restrict__ degi, float* __restrict__ dinv) {
    int i = blockIdx.x * 256 + threadIdx.x;
    if (i < NN) dinv[i] = rsqrtf((float)degi[i] + 1.0f);
}

// ---------------- exclusive prefix scan ----------------
#define SCAN_T 1024
#define SCAN_PER 15
__global__ __launch_bounds__(SCAN_T) void k_scan(const int* __restrict__ degi,
                                                 int* __restrict__ row_ptr) {
    __shared__ int part[SCAN_T];
    const int t = threadIdx.x;
    const int base = t * SCAN_PER;
    int loc[SCAN_PER];
    int s = 0;
#pragma unroll
    for (int i = 0; i < SCAN_PER; i++) {
        int v = (base + i < NN) ? degi[base + i] : 0;
        loc[i] = s; s += v;
    }
    part[t] = s;
    __syncthreads();
    for (int off = 1; off < SCAN_T; off <<= 1) {
        int v = (t >= off) ? part[t - off] : 0;
        __syncthreads();
        part[t] += v;
        __syncthreads();
    }
    int before = (t == 0) ? 0 : part[t - 1];
#pragma unroll
    for (int i = 0; i < SCAN_PER; i++)
        if (base + i < NN) row_ptr[base + i] = before + loc[i];
    if (t == SCAN_T - 1) row_ptr[NN] = part[SCAN_T - 1];
}

__global__ void k_bucket(const int* __restrict__ src, const int* __restrict__ dst,
                         const int* __restrict__ row_ptr, int* __restrict__ cursor,
                         const float* __restrict__ dinv,
                         int* __restrict__ s_idx, float* __restrict__ wts) {
    int e = blockIdx.x * 256 + threadIdx.x;
    if (e >= EE) return;
    int s = src[e], d = dst[e];
    int pos = atomicAdd(&cursor[d], 1);
    int idx = row_ptr[d] + pos;
    s_idx[idx] = s;
    wts[idx] = dinv[s] * dinv[d];
}

// ---------------- x fp32 -> bf16 (pairs) ----------------
__global__ void k_cvtX(const float* __restrict__ x, unsigned* __restrict__ xb) {
    int g = blockIdx.x * 256 + threadIdx.x;       // pair index, grid exact
    float2 v = *(const float2*)&x[(size_t)g * 2];
    xb[g] = pack2_bf16(v.x, v.y);
}

// ---------------- W [K,128] fp32 -> Wt [128,K] bf16 ----------------
__global__ void k_cvtW(const float* __restrict__ W, unsigned short* __restrict__ Wt, int K) {
    int idx = blockIdx.x * 256 + threadIdx.x;
    if (idx >= 128 * K) return;
    int c = idx / K, k = idx % K;
    Wt[idx] = to_bf16(W[(size_t)k * HD + c]);
}

// ---------------- batch-sliced CSR gather-aggregate (linear, no epilogue) ----
// wave per node; F=128: 1 batch/wave; F=64: 2 batches/wave
template<int F>
__global__ __launch_bounds__(256) void k_agg(const unsigned short* __restrict__ Xb,
                                             const int* __restrict__ row_ptr,
                                             const int* __restrict__ s_idx,
                                             const float* __restrict__ wts,
                                             const float* __restrict__ dinv,
                                             unsigned short* __restrict__ Ab) {
    constexpr int LPB = F / 2;
    constexpr int BPW = 64 / LPB;
    const int tid = threadIdx.x;
    const int widx = tid >> 6, lane = tid & 63;
    const int n = blockIdx.x * 4 + widx;
    if (n >= NN) return;
    const int bb = blockIdx.y * BPW + lane / LPB;
    const int fp = lane % LPB;
    const unsigned short* Xrow = Xb + (size_t)bb * NN * F + 2 * fp;

    const int e0 = row_ptr[n], e1 = row_ptr[n + 1];
    const float dv = dinv[n];
    float ax, ay;
    {
        unsigned u = *(const unsigned*)&Xrow[(size_t)n * F];
        float w0 = dv * dv;
        ax = w0 * __uint_as_float(u << 16);
        ay = w0 * __uint_as_float(u & 0xffff0000u);
    }
    for (int c0 = e0; c0 < e1; c0 += 64) {
        int idx = c0 + lane;
        int sv = 0; float wv = 0.f;
        if (idx < e1) { sv = s_idx[idx]; wv = wts[idx]; }
        int cnt = min(64, e1 - c0);
        for (int j = 0; j < cnt; j++) {
            int s = __shfl(sv, j, 64);
            float w = __shfl(wv, j, 64);
            unsigned u = *(const unsigned*)&Xrow[(size_t)s * F];
            ax += w * __uint_as_float(u << 16);
            ay += w * __uint_as_float(u & 0xffff0000u);
        }
    }
    *(unsigned*)&Ab[(size_t)bb * NN * F + (size_t)n * F + 2 * fp] = pack2_bf16(ax, ay);
}

// ---------------- MFMA GEMM + fused epilogue ----------------
// Y[64,128] tile per block; H = relu(Xb@W + bias) -> bf16; g (+)= H . Wfc[:,LIDX]
template<int KD, int LIDX, bool GINIT, bool STOREH>
__global__ __launch_bounds__(256) void k_gemm_ep(const unsigned short* __restrict__ Xb,
                                                 const unsigned short* __restrict__ Wt,
                                                 const float* __restrict__ bias,
                                                 const float* __restrict__ Wfc,
                                                 const float* __restrict__ bfc,
                                                 unsigned short* __restrict__ H,
                                                 float* __restrict__ g) {
    constexpr int NK = KD / 32;
    const int tid = threadIdx.x;
    const int w = tid >> 6, lane = tid & 63;
    const int l15 = lane & 15, lhi = lane >> 4;
    const int row0 = blockIdx.x * 64;
    const int cbase = w * 32;

    bf16x8 B[2][NK];
#pragma unroll
    for (int ct = 0; ct < 2; ct++)
#pragma unroll
        for (int ks = 0; ks < NK; ks++)
            B[ct][ks] = *(const bf16x8*)&Wt[(size_t)(cbase + ct * 16 + l15) * KD + ks * 32 + lhi * 8];

    f32x4 acc[4][2] = {};
#pragma unroll
    for (int ks = 0; ks < NK; ks++) {
        bf16x8 A[4];
#pragma unroll
        for (int rt = 0; rt < 4; rt++)
            A[rt] = *(const bf16x8*)&Xb[(size_t)(row0 + rt * 16 + l15) * KD + ks * 32 + lhi * 8];
#pragma unroll
        for (int rt = 0; rt < 4; rt++)
#pragma unroll
            for (int ct = 0; ct < 2; ct++)
                acc[rt][ct] = __builtin_amdgcn_mfma_f32_16x16x32_bf16(A[rt], B[ct][ks], acc[rt][ct], 0, 0, 0);
    }

    __shared__ float gred[4][64];
    const float bias0 = bias[cbase + l15], bias1 = bias[cbase + 16 + l15];
    const float wf0 = Wfc[(cbase + l15) * 3 + LIDX];
    const float wf1 = Wfc[(cbase + 16 + l15) * 3 + LIDX];
#pragma unroll
    for (int rt = 0; rt < 4; rt++) {
#pragma unroll
        for (int reg = 0; reg < 4; reg++) {
            const int row = row0 + rt * 16 + lhi * 4 + reg;
            float h0 = fmaxf(acc[rt][0][reg] + bias0, 0.f);
            float h1 = fmaxf(acc[rt][1][reg] + bias1, 0.f);
            if (STOREH) {
                H[(size_t)row * 128 + cbase + l15] = to_bf16(h0);
                H[(size_t)row * 128 + cbase + 16 + l15] = to_bf16(h1);
            }
            float p = h0 * wf0 + h1 * wf1;
#pragma unroll
            for (int m = 8; m; m >>= 1) p += __shfl_xor(p, m, 64);
            if (l15 == 0) gred[w][rt * 16 + lhi * 4 + reg] = p;
        }
    }
    __syncthreads();
    if (tid < 64) {
        const int row = row0 + tid;
        if (row < M_ROWS) {
            float s = gred[0][tid] + gred[1][tid] + gred[2][tid] + gred[3][tid];
            if (GINIT) g[row] = bfc[0] + s; else g[row] += s;
        }
    }
}

// ---------------- fc1 partials ----------------
#define FC1_CH 473
__global__ __launch_bounds__(256) void k_fc1part(const float* __restrict__ g,
                                                 const float* __restrict__ Wl1,
                                                 float* __restrict__ part) {
    const int c = blockIdx.x * 64 + (threadIdx.x & 63);
    const int nq = threadIdx.x >> 6;
    const int n0 = blockIdx.y * FC1_CH;
    const int n1 = min(n0 + FC1_CH, NN);
    float acc[BS];
#pragma unroll
    for (int b = 0; b < BS; b++) acc[b] = 0.f;
    for (int n = n0 + nq; n < n1; n += 4) {
        float w = Wl1[(size_t)n * HFC + c];
#pragma unroll
        for (int b = 0; b < BS; b++) acc[b] += g[b * NN + n] * w;
    }
    __shared__ float red[4][64][BS];
    const int cl = threadIdx.x & 63;
#pragma unroll
    for (int b = 0; b < BS; b++) red[nq][cl][b] = acc[b];
    __syncthreads();
    if (nq == 0) {
#pragma unroll
        for (int b = 0; b < BS; b++) {
            float s = red[0][cl][b] + red[1][cl][b] + red[2][cl][b] + red[3][cl][b];
            part[((size_t)blockIdx.y * HFC + c) * BS + b] = s;
        }
    }
}

__global__ __launch_bounds__(512) void k_fc1red(const float* __restrict__ part,
                                                const float* __restrict__ bl1,
                                                float* __restrict__ z) {
    const int c = threadIdx.x;
    float acc[BS];
#pragma unroll
    for (int b = 0; b < BS; b++) acc[b] = 0.f;
    for (int y = 0; y < 32; y++) {
#pragma unroll
        for (int b = 0; b < BS; b++) acc[b] += part[((size_t)y * HFC + c) * BS + b];
    }
    float bb = bl1[c];
#pragma unroll
    for (int b = 0; b < BS; b++) z[b * HFC + c] = fmaxf(acc[b] + bb, 0.f);
}

// ---------------- logits + log_softmax ----------------
__global__ void k_head(const float* __restrict__ z, const float* __restrict__ Wl2,
                       const float* __restrict__ bl2, float* __restrict__ out) {
    __shared__ float lg[BS][NCLS];
    const int t = threadIdx.x;
    if (t < BS * NCLS) {
        int b = t / NCLS, c = t % NCLS;
        float a = bl2[c];
        for (int k = 0; k < HFC; k++) a += z[b * HFC + k] * Wl2[k * NCLS + c];
        lg[b][c] = a;
    }
    __syncthreads();
    if (t < BS * NCLS) {
        int b = t / NCLS, c = t % NCLS;
        float m = -1e30f;
#pragma unroll
        for (int j = 0; j < NCLS; j++) m = fmaxf(m, lg[b][j]);
        float s = 0.f;
#pragma unroll
        for (int j = 0; j < NCLS; j++) s += expf(lg[b][j] - m);
        out[b * NCLS + c] = lg[b][c] - m - logf(s);
    }
}

extern "C" void kernel_launch(void* const* d_in, const int* in_sizes, int n_in,
                              void* d_out, int out_size, void* d_ws, size_t ws_size,
                              hipStream_t stream) {
    const float* x   = (const float*)d_in[0];
    const int*   ei  = (const int*)d_in[1];
    const float* W1  = (const float*)d_in[2];
    const float* b1  = (const float*)d_in[3];
    const float* W2  = (const float*)d_in[4];
    const float* b2  = (const float*)d_in[5];
    const float* W3  = (const float*)d_in[6];
    const float* b3  = (const float*)d_in[7];
    const float* Wfc = (const float*)d_in[8];
    const float* bfc = (const float*)d_in[9];
    const float* Wl1 = (const float*)d_in[10];
    const float* bl1 = (const float*)d_in[11];
    const float* Wl2 = (const float*)d_in[12];
    const float* bl2 = (const float*)d_in[13];
    float* out = (float*)d_out;

    const int* srcp = ei;
    const int* dstp = ei + EE;

    float* ws = (float*)d_ws;
    float* dinv    = ws;                               // 15360
    float* g       = ws + 15360;                       // 121088
    float* z       = ws + 136448;                      // 4096
    float* part    = ws + 140544;                      // 131072
    int*   row_ptr = (int*)(ws + 271616);              // 15488
    int*   cursor  = (int*)(ws + 287104);              // 15360
    int*   degi    = (int*)(ws + 302464);              // 15360
    int*   s_idx   = (int*)(ws + 317824);              // 242176
    float* wts     = ws + 560000;                      // 242176
    unsigned short* Wt1 = (unsigned short*)(ws + 802176);   // 8192 us
    unsigned short* Wt2 = (unsigned short*)(ws + 806272);   // 16384 us
    unsigned short* Wt3 = (unsigned short*)(ws + 814464);   // 16384 us
    unsigned short* xb  = (unsigned short*)(ws + 822656);   // M_PAD*64
    unsigned short* a0  = (unsigned short*)(ws + 4697472);  // M_PAD*64
    unsigned short* B1  = (unsigned short*)(ws + 8572288);  // M_PAD*128
    unsigned short* B2  = (unsigned short*)(ws + 16321920); // M_PAD*128

    const int gemm_grid = M_PAD / 64;                  // 1892
    const dim3 agg_grid((NN + 3) / 4, 0, 1);

    k_init<<<(NN + 255) / 256, 256, 0, stream>>>(degi, cursor);
    k_deg<<<(EE + 255) / 256, 256, 0, stream>>>(dstp, degi);
    k_dinv<<<(NN + 255) / 256, 256, 0, stream>>>(degi, dinv);
    k_scan<<<1, SCAN_T, 0, stream>>>(degi, row_ptr);
    k_bucket<<<(EE + 255) / 256, 256, 0, stream>>>(srcp, dstp, row_ptr, cursor, dinv, s_idx, wts);

    k_cvtX<<<M_ROWS * FIN / 2 / 256, 256, 0, stream>>>(x, (unsigned*)xb);
    k_cvtW<<<(128 * 64 + 255) / 256, 256, 0, stream>>>(W1, Wt1, 64);
    k_cvtW<<<(128 * 128 + 255) / 256, 256, 0, stream>>>(W2, Wt2, 128);
    k_cvtW<<<(128 * 128 + 255) / 256, 256, 0, stream>>>(W3, Wt3, 128);

    // conv1: a0 = agg(xb) [64-wide]; h1(B1) = relu(a0@W1+b1), g = bfc + h1.Wfc0
    k_agg<64><<<dim3((NN + 3) / 4, 4), 256, 0, stream>>>(xb, row_ptr, s_idx, wts, dinv, a0);
    k_gemm_ep<64, 0, true, true><<<gemm_grid, 256, 0, stream>>>(a0, Wt1, b1, Wfc, bfc, B1, g);
    // conv2: a1(B2) = agg(h1); h2(B1) = relu(a1@W2+b2), g += h2.Wfc1
    k_agg<128><<<dim3((NN + 3) / 4, 8), 256, 0, stream>>>(B1, row_ptr, s_idx, wts, dinv, B2);
    k_gemm_ep<128, 1, false, true><<<gemm_grid, 256, 0, stream>>>(B2, Wt2, b2, Wfc, bfc, B1, g);
    // conv3: a2(B2) = agg(h2); g += h3.Wfc2 (h3 not stored)
    k_agg<128><<<dim3((NN + 3) / 4, 8), 256, 0, stream>>>(B1, row_ptr, s_idx, wts, dinv, B2);
    k_gemm_ep<128, 2, false, false><<<gemm_grid, 256, 0, stream>>>(B2, Wt3, b3, Wfc, bfc, B1, g);

    k_fc1part<<<dim3(8, 32), 256, 0, stream>>>(g, Wl1, part);
    k_fc1red<<<1, 512, 0, stream>>>(part, bl1, z);
    k_head<<<1, 128, 0, stream>>>(z, Wl2, bl2, out);
}

// Round 5
// 497.558 us; speedup vs baseline: 23.9959x; 1.2597x over previous
//
#include <hip/hip_runtime.h>
#include <hip/hip_bf16.h>

#define NN 15135
#define BS 8
#define FIN 64
#define HD 128
#define EE 242160
#define HFC 512
#define NCLS 10

#define M_ROWS (BS * NN)          // 121080
#define M_PAD  121088             // 64 * 1892
#define PADE   287616             // >= EE + 3*NN (CSR rows padded to multiple of 4)

typedef __attribute__((ext_vector_type(8))) short bf16x8;
typedef __attribute__((ext_vector_type(4))) float f32x4;

__device__ __forceinline__ unsigned short to_bf16(float f) {
    unsigned u = __float_as_uint(f);
    u = (u + 0x7fffu + ((u >> 16) & 1u)) >> 16;       // RNE
    return (unsigned short)u;
}
__device__ __forceinline__ unsigned pack2_bf16(float lo, float hi) {
    unsigned a = __float_as_uint(lo);
    unsigned b = __float_as_uint(hi);
    a = (a + 0x7fffu + ((a >> 16) & 1u)) >> 16;
    b = (b + 0x7fffu + ((b >> 16) & 1u)) & 0xffff0000u;
    return (a & 0xffffu) | b;
}

// ---------------- degree histogram (int) ----------------
__global__ void k_deg(const int* __restrict__ dst, int* __restrict__ degi) {
    int e = blockIdx.x * 256 + threadIdx.x;
    if (e < EE) atomicAdd(&degi[dst[e]], 1);
}

// ---------------- scan (padded-to-4 degrees) + dinv ----------------
#define SCAN_T 1024
#define SCAN_PER 15
__global__ __launch_bounds__(SCAN_T) void k_scan(const int* __restrict__ degi,
                                                 int* __restrict__ row_ptr,
                                                 float* __restrict__ dinv) {
    __shared__ int part[SCAN_T];
    const int t = threadIdx.x;
    const int base = t * SCAN_PER;
    int loc[SCAN_PER];
    int s = 0;
#pragma unroll
    for (int i = 0; i < SCAN_PER; i++) {
        int d = (base + i < NN) ? degi[base + i] : 0;
        if (base + i < NN) dinv[base + i] = rsqrtf((float)d + 1.0f);
        int pd = (d + 3) & ~3;          // pad row to multiple of 4
        loc[i] = s; s += pd;
    }
    part[t] = s;
    __syncthreads();
    for (int off = 1; off < SCAN_T; off <<= 1) {
        int v = (t >= off) ? part[t - off] : 0;
        __syncthreads();
        part[t] += v;
        __syncthreads();
    }
    int before = (t == 0) ? 0 : part[t - 1];
#pragma unroll
    for (int i = 0; i < SCAN_PER; i++)
        if (base + i < NN) row_ptr[base + i] = before + loc[i];
    if (t == SCAN_T - 1) row_ptr[NN] = part[SCAN_T - 1];
}

// ---------------- bucket fill (padded slots stay s=0,w=0 from memset) ----------
__global__ void k_bucket(const int* __restrict__ src, const int* __restrict__ dst,
                         const int* __restrict__ row_ptr, int* __restrict__ cursor,
                         const float* __restrict__ dinv,
                         int* __restrict__ s_idx, float* __restrict__ wts) {
    int e = blockIdx.x * 256 + threadIdx.x;
    if (e >= EE) return;
    int s = src[e], d = dst[e];
    int pos = atomicAdd(&cursor[d], 1);
    int idx = row_ptr[d] + pos;
    s_idx[idx] = s;
    wts[idx] = dinv[s] * dinv[d];
}

// ---------------- x fp32 -> bf16 (pairs) ----------------
__global__ void k_cvtX(const float* __restrict__ x, unsigned* __restrict__ xb) {
    int g = blockIdx.x * 256 + threadIdx.x;
    float2 v = *(const float2*)&x[(size_t)g * 2];
    xb[g] = pack2_bf16(v.x, v.y);
}

// ---------------- all 3 W [K,128] fp32 -> Wt [128,K] bf16, concatenated -------
__global__ void k_cvtW(const float* __restrict__ W1, const float* __restrict__ W2,
                       const float* __restrict__ W3, unsigned short* __restrict__ Wt) {
    int idx = blockIdx.x * 256 + threadIdx.x;     // 0..40959
    const float* W; int K, base;
    if (idx < 8192)       { W = W1; K = 64;  base = idx; }
    else if (idx < 24576) { W = W2; K = 128; base = idx - 8192; }
    else                  { W = W3; K = 128; base = idx - 24576; }
    int c = base / K, k = base % K;
    Wt[idx] = to_bf16(W[(size_t)k * HD + c]);
}

// ---------------- CSR gather-aggregate: scalar CSR + 4-deep ILP --------------
// wave per node; F=128: 1 batch/wave (y=0..7); F=64: 2 batches/wave (y=0..3)
template<int F>
__global__ __launch_bounds__(256) void k_agg(const unsigned short* __restrict__ Xb,
                                             const int* __restrict__ row_ptr,
                                             const int* __restrict__ s_idx,
                                             const float* __restrict__ wts,
                                             const float* __restrict__ dinv,
                                             unsigned short* __restrict__ Ab) {
    constexpr int LPB = F / 2;          // lanes covering one row
    constexpr int BPW = 64 / LPB;       // batches per wave
    const int tid = threadIdx.x;
    const int widx = tid >> 6, lane = tid & 63;
    const int n = blockIdx.x * 4 + widx;
    if (n >= NN) return;
    const int bb = blockIdx.y * BPW + lane / LPB;
    const int fp = lane % LPB;
    const unsigned short* Xs = Xb + (size_t)bb * NN * F + 2 * fp;

    const int e0 = __builtin_amdgcn_readfirstlane(row_ptr[n]);
    const int e1 = __builtin_amdgcn_readfirstlane(row_ptr[n + 1]);
    const float dv = dinv[n];

    float ax, ay;
    {
        unsigned u = *(const unsigned*)&Xs[(size_t)n * F];
        float w0 = dv * dv;
        ax = w0 * __uint_as_float(u << 16);
        ay = w0 * __uint_as_float(u & 0xffff0000u);
    }
    for (int c = e0; c < e1; c += 4) {
        int s0 = s_idx[c + 0], s1 = s_idx[c + 1], s2 = s_idx[c + 2], s3 = s_idx[c + 3];
        float w0 = wts[c + 0], w1 = wts[c + 1], w2 = wts[c + 2], w3 = wts[c + 3];
        unsigned u0 = *(const unsigned*)&Xs[(size_t)s0 * F];
        unsigned u1 = *(const unsigned*)&Xs[(size_t)s1 * F];
        unsigned u2 = *(const unsigned*)&Xs[(size_t)s2 * F];
        unsigned u3 = *(const unsigned*)&Xs[(size_t)s3 * F];
        ax += w0 * __uint_as_float(u0 << 16); ay += w0 * __uint_as_float(u0 & 0xffff0000u);
        ax += w1 * __uint_as_float(u1 << 16); ay += w1 * __uint_as_float(u1 & 0xffff0000u);
        ax += w2 * __uint_as_float(u2 << 16); ay += w2 * __uint_as_float(u2 & 0xffff0000u);
        ax += w3 * __uint_as_float(u3 << 16); ay += w3 * __uint_as_float(u3 & 0xffff0000u);
    }
    *(unsigned*)&Ab[(size_t)bb * NN * F + (size_t)n * F + 2 * fp] = pack2_bf16(ax, ay);
}

// ---------------- MFMA GEMM + fused epilogue ----------------
template<int KD, int LIDX, bool GINIT, bool STOREH>
__global__ __launch_bounds__(256) void k_gemm_ep(const unsigned short* __restrict__ Xb,
                                                 const unsigned short* __restrict__ Wt,
                                                 const float* __restrict__ bias,
                                                 const float* __restrict__ Wfc,
                                                 const float* __restrict__ bfc,
                                                 unsigned short* __restrict__ H,
                                                 float* __restrict__ g) {
    constexpr int NK = KD / 32;
    const int tid = threadIdx.x;
    const int w = tid >> 6, lane = tid & 63;
    const int l15 = lane & 15, lhi = lane >> 4;
    const int row0 = blockIdx.x * 64;
    const int cbase = w * 32;

    bf16x8 B[2][NK];
#pragma unroll
    for (int ct = 0; ct < 2; ct++)
#pragma unroll
        for (int ks = 0; ks < NK; ks++)
            B[ct][ks] = *(const bf16x8*)&Wt[(size_t)(cbase + ct * 16 + l15) * KD + ks * 32 + lhi * 8];

    f32x4 acc[4][2] = {};
#pragma unroll
    for (int ks = 0; ks < NK; ks++) {
        bf16x8 A[4];
#pragma unroll
        for (int rt = 0; rt < 4; rt++)
            A[rt] = *(const bf16x8*)&Xb[(size_t)(row0 + rt * 16 + l15) * KD + ks * 32 + lhi * 8];
#pragma unroll
        for (int rt = 0; rt < 4; rt++)
#pragma unroll
            for (int ct = 0; ct < 2; ct++)
                acc[rt][ct] = __builtin_amdgcn_mfma_f32_16x16x32_bf16(A[rt], B[ct][ks], acc[rt][ct], 0, 0, 0);
    }

    __shared__ float gred[4][64];
    const float bias0 = bias[cbase + l15], bias1 = bias[cbase + 16 + l15];
    const float wf0 = Wfc[(cbase + l15) * 3 + LIDX];
    const float wf1 = Wfc[(cbase + 16 + l15) * 3 + LIDX];
#pragma unroll
    for (int rt = 0; rt < 4; rt++) {
#pragma unroll
        for (int reg = 0; reg < 4; reg++) {
            const int row = row0 + rt * 16 + lhi * 4 + reg;
            float h0 = fmaxf(acc[rt][0][reg] + bias0, 0.f);
            float h1 = fmaxf(acc[rt][1][reg] + bias1, 0.f);
            if (STOREH) {
                H[(size_t)row * 128 + cbase + l15] = to_bf16(h0);
                H[(size_t)row * 128 + cbase + 16 + l15] = to_bf16(h1);
            }
            float p = h0 * wf0 + h1 * wf1;
#pragma unroll
            for (int m = 8; m; m >>= 1) p += __shfl_xor(p, m, 64);
            if (l15 == 0) gred[w][rt * 16 + lhi * 4 + reg] = p;
        }
    }
    __syncthreads();
    if (tid < 64) {
        const int row = row0 + tid;
        if (row < M_ROWS) {
            float s = gred[0][tid] + gred[1][tid] + gred[2][tid] + gred[3][tid];
            if (GINIT) g[row] = bfc[0] + s; else g[row] += s;
        }
    }
}

// ---------------- fc1 partials ----------------
#define FC1_CH 473
__global__ __launch_bounds__(256) void k_fc1part(const float* __restrict__ g,
                                                 const float* __restrict__ Wl1,
                                                 float* __restrict__ part) {
    const int c = blockIdx.x * 64 + (threadIdx.x & 63);
    const int nq = threadIdx.x >> 6;
    const int n0 = blockIdx.y * FC1_CH;
    const int n1 = min(n0 + FC1_CH, NN);
    float acc[BS];
#pragma unroll
    for (int b = 0; b < BS; b++) acc[b] = 0.f;
    for (int n = n0 + nq; n < n1; n += 4) {
        float w = Wl1[(size_t)n * HFC + c];
#pragma unroll
        for (int b = 0; b < BS; b++) acc[b] += g[b * NN + n] * w;
    }
    __shared__ float red[4][64][BS];
    const int cl = threadIdx.x & 63;
#pragma unroll
    for (int b = 0; b < BS; b++) red[nq][cl][b] = acc[b];
    __syncthreads();
    if (nq == 0) {
#pragma unroll
        for (int b = 0; b < BS; b++) {
            float s = red[0][cl][b] + red[1][cl][b] + red[2][cl][b] + red[3][cl][b];
            part[((size_t)blockIdx.y * HFC + c) * BS + b] = s;
        }
    }
}

// ---------------- fc1 reduce + relu + logits + log_softmax (merged) ----------
__global__ __launch_bounds__(512) void k_fc1red_head(const float* __restrict__ part,
                                                     const float* __restrict__ bl1,
                                                     const float* __restrict__ Wl2,
                                                     const float* __restrict__ bl2,
                                                     float* __restrict__ out) {
    __shared__ float zs[HFC * BS];        // [c][b], 16 KB
    __shared__ float lg[BS * NCLS];
    const int c = threadIdx.x;
    float acc[BS];
#pragma unroll
    for (int b = 0; b < BS; b++) acc[b] = 0.f;
    for (int y = 0; y < 32; y++) {
#pragma unroll
        for (int b = 0; b < BS; b++) acc[b] += part[((size_t)y * HFC + c) * BS + b];
    }
    float bb = bl1[c];
#pragma unroll
    for (int b = 0; b < BS; b++) zs[c * BS + b] = fmaxf(acc[b] + bb, 0.f);
    __syncthreads();
    const int t = threadIdx.x;
    if (t < BS * NCLS) {
        int b = t / NCLS, cc = t % NCLS;
        float a = bl2[cc];
        for (int k = 0; k < HFC; k++) a += zs[k * BS + b] * Wl2[k * NCLS + cc];
        lg[b * NCLS + cc] = a;
    }
    __syncthreads();
    if (t < BS * NCLS) {
        int b = t / NCLS, cc = t % NCLS;
        float m = -1e30f;
#pragma unroll
        for (int j = 0; j < NCLS; j++) m = fmaxf(m, lg[b * NCLS + j]);
        float s = 0.f;
#pragma unroll
        for (int j = 0; j < NCLS; j++) s += expf(lg[b * NCLS + j] - m);
        out[b * NCLS + cc] = lg[b * NCLS + cc] - m - logf(s);
    }
}

extern "C" void kernel_launch(void* const* d_in, const int* in_sizes, int n_in,
                              void* d_out, int out_size, void* d_ws, size_t ws_size,
                              hipStream_t stream) {
    const float* x   = (const float*)d_in[0];
    const int*   ei  = (const int*)d_in[1];
    const float* W1  = (const float*)d_in[2];
    const float* b1  = (const float*)d_in[3];
    const float* W2  = (const float*)d_in[4];
    const float* b2  = (const float*)d_in[5];
    const float* W3  = (const float*)d_in[6];
    const float* b3  = (const float*)d_in[7];
    const float* Wfc = (const float*)d_in[8];
    const float* bfc = (const float*)d_in[9];
    const float* Wl1 = (const float*)d_in[10];
    const float* bl1 = (const float*)d_in[11];
    const float* Wl2 = (const float*)d_in[12];
    const float* bl2 = (const float*)d_in[13];
    float* out = (float*)d_out;

    const int* srcp = ei;
    const int* dstp = ei + EE;

    float* ws = (float*)d_ws;
    float* dinv    = ws;                               // 15360
    float* g       = ws + 15360;                       // 121088
    float* part    = ws + 136448;                      // 131072 -> 267520
    int*   degi    = (int*)(ws + 267520);              // 15360
    int*   cursor  = (int*)(ws + 282880);              // 15360  (contiguous w/ degi)
    int*   row_ptr = (int*)(ws + 298240);              // 15488
    int*   s_idx   = (int*)(ws + 313728);              // PADE
    float* wts     = ws + 601344;                      // PADE   (contiguous w/ s_idx)
    unsigned short* Wt  = (unsigned short*)(ws + 888960);   // 40960 ushorts
    unsigned short* Wt1 = Wt;
    unsigned short* Wt2 = Wt + 8192;
    unsigned short* Wt3 = Wt + 24576;
    unsigned short* xb  = (unsigned short*)(ws + 909440);   // 64-wide
    unsigned short* a0  = (unsigned short*)(ws + 4784256);  // 64-wide
    unsigned short* B1  = (unsigned short*)(ws + 8659072);  // 128-wide
    unsigned short* B2  = (unsigned short*)(ws + 16408704); // 128-wide

    const int gemm_grid = M_PAD / 64;                  // 1892

    hipMemsetAsync(degi, 0, 2 * 15360 * sizeof(int), stream);        // degi + cursor
    hipMemsetAsync(s_idx, 0, 2 * PADE * sizeof(int), stream);        // s_idx + wts
    k_deg<<<(EE + 255) / 256, 256, 0, stream>>>(dstp, degi);
    k_scan<<<1, SCAN_T, 0, stream>>>(degi, row_ptr, dinv);
    k_bucket<<<(EE + 255) / 256, 256, 0, stream>>>(srcp, dstp, row_ptr, cursor, dinv, s_idx, wts);

    k_cvtX<<<M_ROWS * FIN / 2 / 256, 256, 0, stream>>>(x, (unsigned*)xb);
    k_cvtW<<<160, 256, 0, stream>>>(W1, W2, W3, Wt);

    // conv1: a0 = agg(xb) [64-wide]; h1(B1) = relu(a0@W1+b1), g = bfc + h1.Wfc0
    k_agg<64><<<dim3((NN + 3) / 4, 4), 256, 0, stream>>>(xb, row_ptr, s_idx, wts, dinv, a0);
    k_gemm_ep<64, 0, true, true><<<gemm_grid, 256, 0, stream>>>(a0, Wt1, b1, Wfc, bfc, B1, g);
    // conv2: a1(B2) = agg(h1); h2(B1) = relu(a1@W2+b2), g += h2.Wfc1
    k_agg<128><<<dim3((NN + 3) / 4, 8), 256, 0, stream>>>(B1, row_ptr, s_idx, wts, dinv, B2);
    k_gemm_ep<128, 1, false, true><<<gemm_grid, 256, 0, stream>>>(B2, Wt2, b2, Wfc, bfc, B1, g);
    // conv3: a2(B2) = agg(h2); g += h3.Wfc2 (h3 not stored)
    k_agg<128><<<dim3((NN + 3) / 4, 8), 256, 0, stream>>>(B1, row_ptr, s_idx, wts, dinv, B2);
    k_gemm_ep<128, 2, false, false><<<gemm_grid, 256, 0, stream>>>(B2, Wt3, b3, Wfc, bfc, B1, g);

    k_fc1part<<<dim3(8, 32), 256, 0, stream>>>(g, Wl1, part);
    k_fc1red_head<<<1, 512, 0, stream>>>(part, bl1, Wl2, bl2, out);
}

// Round 6
// 491.853 us; speedup vs baseline: 24.2743x; 1.0116x over previous
//
#include <hip/hip_runtime.h>
#include <hip/hip_bf16.h>

#define NN 15135
#define BS 8
#define FIN 64
#define HD 128
#define EE 242160
#define HFC 512
#define NCLS 10

#define M_ROWS (BS * NN)          // 121080
#define M_PAD  121088             // 64 * 1892
#define PADE   287616             // >= EE + 3*NN (CSR rows padded to multiple of 4)

#define NCH 237                   // fc1 chunks of 64 rows: 237*64 = 15168 >= NN
#define NPLANES (NCH * 2)         // 474 partial planes

typedef __attribute__((ext_vector_type(8))) short bf16x8;
typedef __attribute__((ext_vector_type(4))) float f32x4;

__device__ __forceinline__ unsigned short to_bf16(float f) {
    unsigned u = __float_as_uint(f);
    u = (u + 0x7fffu + ((u >> 16) & 1u)) >> 16;       // RNE
    return (unsigned short)u;
}
__device__ __forceinline__ unsigned pack2_bf16(float lo, float hi) {
    unsigned a = __float_as_uint(lo);
    unsigned b = __float_as_uint(hi);
    a = (a + 0x7fffu + ((a >> 16) & 1u)) >> 16;
    b = (b + 0x7fffu + ((b >> 16) & 1u)) & 0xffff0000u;
    return (a & 0xffffu) | b;
}

// ---------------- degree histogram (int) ----------------
__global__ void k_deg(const int* __restrict__ dst, int* __restrict__ degi) {
    int e = blockIdx.x * 256 + threadIdx.x;
    if (e < EE) atomicAdd(&degi[dst[e]], 1);
}

// ---------------- scan (padded-to-4 degrees) + dinv ----------------
#define SCAN_T 1024
#define SCAN_PER 15
__global__ __launch_bounds__(SCAN_T) void k_scan(const int* __restrict__ degi,
                                                 int* __restrict__ row_ptr,
                                                 float* __restrict__ dinv) {
    __shared__ int part[SCAN_T];
    const int t = threadIdx.x;
    const int base = t * SCAN_PER;
    int loc[SCAN_PER];
    int s = 0;
#pragma unroll
    for (int i = 0; i < SCAN_PER; i++) {
        int d = (base + i < NN) ? degi[base + i] : 0;
        if (base + i < NN) dinv[base + i] = rsqrtf((float)d + 1.0f);
        int pd = (d + 3) & ~3;          // pad row to multiple of 4
        loc[i] = s; s += pd;
    }
    part[t] = s;
    __syncthreads();
    for (int off = 1; off < SCAN_T; off <<= 1) {
        int v = (t >= off) ? part[t - off] : 0;
        __syncthreads();
        part[t] += v;
        __syncthreads();
    }
    int before = (t == 0) ? 0 : part[t - 1];
#pragma unroll
    for (int i = 0; i < SCAN_PER; i++)
        if (base + i < NN) row_ptr[base + i] = before + loc[i];
    if (t == SCAN_T - 1) row_ptr[NN] = part[SCAN_T - 1];
}

// ---------------- bucket fill (padded slots stay s=0,w=0 from memset) ----------
__global__ void k_bucket(const int* __restrict__ src, const int* __restrict__ dst,
                         const int* __restrict__ row_ptr, int* __restrict__ cursor,
                         const float* __restrict__ dinv,
                         int* __restrict__ s_idx, float* __restrict__ wts) {
    int e = blockIdx.x * 256 + threadIdx.x;
    if (e >= EE) return;
    int s = src[e], d = dst[e];
    int pos = atomicAdd(&cursor[d], 1);
    int idx = row_ptr[d] + pos;
    s_idx[idx] = s;
    wts[idx] = dinv[s] * dinv[d];
}

// ---------------- all 3 W [K,128] fp32 -> Wt [128,K] bf16, concatenated -------
__global__ void k_cvtW(const float* __restrict__ W1, const float* __restrict__ W2,
                       const float* __restrict__ W3, unsigned short* __restrict__ Wt) {
    int idx = blockIdx.x * 256 + threadIdx.x;     // 0..40959
    const float* W; int K, base;
    if (idx < 8192)       { W = W1; K = 64;  base = idx; }
    else if (idx < 24576) { W = W2; K = 128; base = idx - 8192; }
    else                  { W = W3; K = 128; base = idx - 24576; }
    int c = base / K, k = base % K;
    Wt[idx] = to_bf16(W[(size_t)k * HD + c]);
}

// ---------------- conv1 aggregate: gather fp32 x directly, emit bf16 ---------
// wave per node, 2 batches/wave (32 lanes x float2 per row); grid.y = 4
__global__ __launch_bounds__(256) void k_aggx(const float* __restrict__ x,
                                              const int* __restrict__ row_ptr,
                                              const int* __restrict__ s_idx,
                                              const float* __restrict__ wts,
                                              const float* __restrict__ dinv,
                                              unsigned short* __restrict__ Ab) {
    const int tid = threadIdx.x;
    const int widx = tid >> 6, lane = tid & 63;
    const int n = blockIdx.x * 4 + widx;
    if (n >= NN) return;
    const int bb = blockIdx.y * 2 + (lane >> 5);
    const int fp = lane & 31;
    const float* Xs = x + (size_t)bb * NN * FIN + 2 * fp;

    const int e0 = __builtin_amdgcn_readfirstlane(row_ptr[n]);
    const int e1 = __builtin_amdgcn_readfirstlane(row_ptr[n + 1]);
    const float dv = dinv[n];

    float2 v = *(const float2*)&Xs[(size_t)n * FIN];
    float ax = dv * dv * v.x, ay = dv * dv * v.y;

    for (int c = e0; c < e1; c += 4) {
        int s0 = s_idx[c + 0], s1 = s_idx[c + 1], s2 = s_idx[c + 2], s3 = s_idx[c + 3];
        float w0 = wts[c + 0], w1 = wts[c + 1], w2 = wts[c + 2], w3 = wts[c + 3];
        float2 u0 = *(const float2*)&Xs[(size_t)s0 * FIN];
        float2 u1 = *(const float2*)&Xs[(size_t)s1 * FIN];
        float2 u2 = *(const float2*)&Xs[(size_t)s2 * FIN];
        float2 u3 = *(const float2*)&Xs[(size_t)s3 * FIN];
        ax += w0 * u0.x; ay += w0 * u0.y;
        ax += w1 * u1.x; ay += w1 * u1.y;
        ax += w2 * u2.x; ay += w2 * u2.y;
        ax += w3 * u3.x; ay += w3 * u3.y;
    }
    *(unsigned*)&Ab[(size_t)bb * NN * FIN + (size_t)n * FIN + 2 * fp] = pack2_bf16(ax, ay);
}

// ---------------- CSR gather-aggregate (bf16): scalar CSR + 4-deep ILP -------
__global__ __launch_bounds__(256) void k_agg128(const unsigned short* __restrict__ Xb,
                                                const int* __restrict__ row_ptr,
                                                const int* __restrict__ s_idx,
                                                const float* __restrict__ wts,
                                                const float* __restrict__ dinv,
                                                unsigned short* __restrict__ Ab) {
    const int tid = threadIdx.x;
    const int widx = tid >> 6, lane = tid & 63;
    const int n = blockIdx.x * 4 + widx;
    if (n >= NN) return;
    const int bb = blockIdx.y;
    const int fp = lane;
    const unsigned short* Xs = Xb + (size_t)bb * NN * HD + 2 * fp;

    const int e0 = __builtin_amdgcn_readfirstlane(row_ptr[n]);
    const int e1 = __builtin_amdgcn_readfirstlane(row_ptr[n + 1]);
    const float dv = dinv[n];

    float ax, ay;
    {
        unsigned u = *(const unsigned*)&Xs[(size_t)n * HD];
        float w0 = dv * dv;
        ax = w0 * __uint_as_float(u << 16);
        ay = w0 * __uint_as_float(u & 0xffff0000u);
    }
    for (int c = e0; c < e1; c += 4) {
        int s0 = s_idx[c + 0], s1 = s_idx[c + 1], s2 = s_idx[c + 2], s3 = s_idx[c + 3];
        float w0 = wts[c + 0], w1 = wts[c + 1], w2 = wts[c + 2], w3 = wts[c + 3];
        unsigned u0 = *(const unsigned*)&Xs[(size_t)s0 * HD];
        unsigned u1 = *(const unsigned*)&Xs[(size_t)s1 * HD];
        unsigned u2 = *(const unsigned*)&Xs[(size_t)s2 * HD];
        unsigned u3 = *(const unsigned*)&Xs[(size_t)s3 * HD];
        ax += w0 * __uint_as_float(u0 << 16); ay += w0 * __uint_as_float(u0 & 0xffff0000u);
        ax += w1 * __uint_as_float(u1 << 16); ay += w1 * __uint_as_float(u1 & 0xffff0000u);
        ax += w2 * __uint_as_float(u2 << 16); ay += w2 * __uint_as_float(u2 & 0xffff0000u);
        ax += w3 * __uint_as_float(u3 << 16); ay += w3 * __uint_as_float(u3 & 0xffff0000u);
    }
    *(unsigned*)&Ab[(size_t)bb * NN * HD + (size_t)n * HD + 2 * fp] = pack2_bf16(ax, ay);
}

// ---------------- MFMA GEMM + fused epilogue ----------------
template<int KD, int LIDX, bool GINIT, bool STOREH>
__global__ __launch_bounds__(256) void k_gemm_ep(const unsigned short* __restrict__ Xb,
                                                 const unsigned short* __restrict__ Wt,
                                                 const float* __restrict__ bias,
                                                 const float* __restrict__ Wfc,
                                                 const float* __restrict__ bfc,
                                                 unsigned short* __restrict__ H,
                                                 float* __restrict__ g) {
    constexpr int NK = KD / 32;
    const int tid = threadIdx.x;
    const int w = tid >> 6, lane = tid & 63;
    const int l15 = lane & 15, lhi = lane >> 4;
    const int row0 = blockIdx.x * 64;
    const int cbase = w * 32;

    bf16x8 B[2][NK];
#pragma unroll
    for (int ct = 0; ct < 2; ct++)
#pragma unroll
        for (int ks = 0; ks < NK; ks++)
            B[ct][ks] = *(const bf16x8*)&Wt[(size_t)(cbase + ct * 16 + l15) * KD + ks * 32 + lhi * 8];

    f32x4 acc[4][2] = {};
#pragma unroll
    for (int ks = 0; ks < NK; ks++) {
        bf16x8 A[4];
#pragma unroll
        for (int rt = 0; rt < 4; rt++)
            A[rt] = *(const bf16x8*)&Xb[(size_t)(row0 + rt * 16 + l15) * KD + ks * 32 + lhi * 8];
#pragma unroll
        for (int rt = 0; rt < 4; rt++)
#pragma unroll
            for (int ct = 0; ct < 2; ct++)
                acc[rt][ct] = __builtin_amdgcn_mfma_f32_16x16x32_bf16(A[rt], B[ct][ks], acc[rt][ct], 0, 0, 0);
    }

    __shared__ float gred[4][64];
    const float bias0 = bias[cbase + l15], bias1 = bias[cbase + 16 + l15];
    const float wf0 = Wfc[(cbase + l15) * 3 + LIDX];
    const float wf1 = Wfc[(cbase + 16 + l15) * 3 + LIDX];
#pragma unroll
    for (int rt = 0; rt < 4; rt++) {
#pragma unroll
        for (int reg = 0; reg < 4; reg++) {
            const int row = row0 + rt * 16 + lhi * 4 + reg;
            float h0 = fmaxf(acc[rt][0][reg] + bias0, 0.f);
            float h1 = fmaxf(acc[rt][1][reg] + bias1, 0.f);
            if (STOREH) {
                H[(size_t)row * 128 + cbase + l15] = to_bf16(h0);
                H[(size_t)row * 128 + cbase + 16 + l15] = to_bf16(h1);
            }
            float p = h0 * wf0 + h1 * wf1;
#pragma unroll
            for (int m = 8; m; m >>= 1) p += __shfl_xor(p, m, 64);
            if (l15 == 0) gred[w][rt * 16 + lhi * 4 + reg] = p;
        }
    }
    __syncthreads();
    if (tid < 64) {
        const int row = row0 + tid;
        if (row < M_ROWS) {
            float s = gred[0][tid] + gred[1][tid] + gred[2][tid] + gred[3][tid];
            if (GINIT) g[row] = bfc[0] + s; else g[row] += s;
        }
    }
}

// ---------------- fc1 partials: 237 blocks x 64-row chunks, float4 loads -----
// part layout [plane][b][c] (plane = chunk*2 + stream)
__global__ __launch_bounds__(256) void k_fc1part(const float* __restrict__ g,
                                                 const float* __restrict__ Wl1,
                                                 float* __restrict__ part) {
    const int ct = threadIdx.x & 127;     // cols 4*ct .. 4*ct+3
    const int st = threadIdx.x >> 7;      // 0,1
    const int n0 = blockIdx.x * 64;
    __shared__ float gs[BS][64];
    for (int i = threadIdx.x; i < BS * 64; i += 256) {
        int b = i >> 6, j = i & 63;
        int n = n0 + j;
        gs[b][j] = (n < NN) ? g[b * NN + n] : 0.f;
    }
    __syncthreads();

    f32x4 acc[BS] = {};
    const int jend = min(64, NN - n0);
#pragma unroll 4
    for (int j = st; j < jend; j += 2) {
        f32x4 wv = *(const f32x4*)&Wl1[(size_t)(n0 + j) * HFC + 4 * ct];
#pragma unroll
        for (int b = 0; b < BS; b++) {
            float gv = gs[b][j];
            acc[b] += gv * wv;
        }
    }
    float* p = &part[((size_t)(blockIdx.x * 2 + st)) * (BS * HFC)];
#pragma unroll
    for (int b = 0; b < BS; b++)
        *(f32x4*)&p[b * HFC + 4 * ct] = acc[b];
}

// ---------------- fc1 reduce: z = relu(sum part + bl1) ----------------
__global__ __launch_bounds__(128) void k_fc1red(const float* __restrict__ part,
                                                const float* __restrict__ bl1,
                                                float* __restrict__ z) {
    const int idx = blockIdx.x * 128 + threadIdx.x;   // 0..4095 = b*512 + c
    float s = 0.f;
#pragma unroll 8
    for (int y = 0; y < NPLANES; y++) s += part[(size_t)y * (BS * HFC) + idx];
    const int c = idx & 511;
    z[idx] = fmaxf(s + bl1[c], 0.f);
}

// ---------------- logits + log_softmax ----------------
__global__ void k_head(const float* __restrict__ z, const float* __restrict__ Wl2,
                       const float* __restrict__ bl2, float* __restrict__ out) {
    __shared__ float lg[BS][NCLS];
    const int t = threadIdx.x;
    if (t < BS * NCLS) {
        int b = t / NCLS, c = t % NCLS;
        float a = bl2[c];
        for (int k = 0; k < HFC; k++) a += z[b * HFC + k] * Wl2[k * NCLS + c];
        lg[b][c] = a;
    }
    __syncthreads();
    if (t < BS * NCLS) {
        int b = t / NCLS, c = t % NCLS;
        float m = -1e30f;
#pragma unroll
        for (int j = 0; j < NCLS; j++) m = fmaxf(m, lg[b][j]);
        float s = 0.f;
#pragma unroll
        for (int j = 0; j < NCLS; j++) s += expf(lg[b][j] - m);
        out[b * NCLS + c] = lg[b][c] - m - logf(s);
    }
}

extern "C" void kernel_launch(void* const* d_in, const int* in_sizes, int n_in,
                              void* d_out, int out_size, void* d_ws, size_t ws_size,
                              hipStream_t stream) {
    const float* x   = (const float*)d_in[0];
    const int*   ei  = (const int*)d_in[1];
    const float* W1  = (const float*)d_in[2];
    const float* b1  = (const float*)d_in[3];
    const float* W2  = (const float*)d_in[4];
    const float* b2  = (const float*)d_in[5];
    const float* W3  = (const float*)d_in[6];
    const float* b3  = (const float*)d_in[7];
    const float* Wfc = (const float*)d_in[8];
    const float* bfc = (const float*)d_in[9];
    const float* Wl1 = (const float*)d_in[10];
    const float* bl1 = (const float*)d_in[11];
    const float* Wl2 = (const float*)d_in[12];
    const float* bl2 = (const float*)d_in[13];
    float* out = (float*)d_out;

    const int* srcp = ei;
    const int* dstp = ei + EE;

    float* ws = (float*)d_ws;
    float* dinv    = ws;                               // 15360
    float* g       = ws + 15360;                       // 121088
    float* z       = ws + 136448;                      // 4096
    float* part    = ws + 140544;                      // 474*4096 = 1941504
    int*   degi    = (int*)(ws + 2082048);             // 15360
    int*   cursor  = (int*)(ws + 2097408);             // 15360 (contiguous w/ degi)
    int*   row_ptr = (int*)(ws + 2112768);             // 15488
    int*   s_idx   = (int*)(ws + 2128256);             // PADE
    float* wts     = ws + 2415872;                     // PADE (contiguous w/ s_idx)
    unsigned short* Wt  = (unsigned short*)(ws + 2703488);  // 40960 ushorts
    unsigned short* Wt1 = Wt;
    unsigned short* Wt2 = Wt + 8192;
    unsigned short* Wt3 = Wt + 24576;
    unsigned short* a0  = (unsigned short*)(ws + 2723968);  // M_PAD*64 us
    unsigned short* B1  = (unsigned short*)(ws + 6598784);  // M_PAD*128 us
    unsigned short* B2  = (unsigned short*)(ws + 14348416); // M_PAD*128 us

    const int gemm_grid = M_PAD / 64;                  // 1892

    hipMemsetAsync(degi, 0, 2 * 15360 * sizeof(int), stream);        // degi + cursor
    hipMemsetAsync(s_idx, 0, 2 * PADE * sizeof(int), stream);        // s_idx + wts
    k_deg<<<(EE + 255) / 256, 256, 0, stream>>>(dstp, degi);
    k_scan<<<1, SCAN_T, 0, stream>>>(degi, row_ptr, dinv);
    k_bucket<<<(EE + 255) / 256, 256, 0, stream>>>(srcp, dstp, row_ptr, cursor, dinv, s_idx, wts);
    k_cvtW<<<160, 256, 0, stream>>>(W1, W2, W3, Wt);

    // conv1: a0 = agg(x)[fp32->bf16, 64-wide]; h1(B1) = relu(a0@W1+b1), g = bfc + h1.Wfc0
    k_aggx<<<dim3((NN + 3) / 4, 4), 256, 0, stream>>>(x, row_ptr, s_idx, wts, dinv, a0);
    k_gemm_ep<64, 0, true, true><<<gemm_grid, 256, 0, stream>>>(a0, Wt1, b1, Wfc, bfc, B1, g);
    // conv2: a1(B2) = agg(h1); h2(B1) = relu(a1@W2+b2), g += h2.Wfc1
    k_agg128<<<dim3((NN + 3) / 4, 8), 256, 0, stream>>>(B1, row_ptr, s_idx, wts, dinv, B2);
    k_gemm_ep<128, 1, false, true><<<gemm_grid, 256, 0, stream>>>(B2, Wt2, b2, Wfc, bfc, B1, g);
    // conv3: a2(B2) = agg(h2); g += h3.Wfc2 (h3 not stored)
    k_agg128<<<dim3((NN + 3) / 4, 8), 256, 0, stream>>>(B1, row_ptr, s_idx, wts, dinv, B2);
    k_gemm_ep<128, 2, false, false><<<gemm_grid, 256, 0, stream>>>(B2, Wt3, b3, Wfc, bfc, B1, g);

    k_fc1part<<<NCH, 256, 0, stream>>>(g, Wl1, part);
    k_fc1red<<<32, 128, 0, stream>>>(part, bl1, z);
    k_head<<<1, 128, 0, stream>>>(z, Wl2, bl2, out);
}